// Round 14
// baseline (657.375 us; speedup 1.0000x reference)
//
#include <hip/hip_runtime.h>
#include <cstdio>
#include <cstdint>

static constexpr int  MPIX   = 51529;   // 227*227
static constexpr int  NBATCH = 8;
static constexpr int  NTH    = 256;
static constexpr int  HD     = 257;     // rank histogram dim (0..256)
static constexpr int  HP     = 260;     // padded H pitch
static constexpr int  GW     = 3;       // rank-group width (measured-fast phase2 shape)
static constexpr int  GRP    = 86;      // ceil(257/3); 8*86 = 688 = grid size
static constexpr int  NCH    = 51;      // bin chunks of 1024 px; 8*51 = 408 bin tasks
static constexpr int  NSCAN  = 65;      // col-quads per batch; 8*65 = 520 scan tasks
static constexpr int  CAPG   = 4096;    // records per (b,g) (mean ~330 post-filter)
static constexpr int  NBLK   = NBATCH * GRP;   // 688

// ws layout (float slots). Counters at 0 (zeroed by the memset node each call).
static constexpr long DONEBIN_OFF = 0;    // 8 ints
static constexpr long DONEP2_OFF  = 8;    // 8 ints
static constexpr long DONESC_OFF  = 16;   // 8 ints
static constexpr long DONEMV_OFF  = 24;   // 1 int
static constexpr long GCUR_OFF    = 32;   // 688 ints
static constexpr long CTR_BYTES   = (GCUR_OFF + NBLK) * 4;   // 2880 B memset
static constexpr long H_OFF       = 1024;
static constexpr long H_SZ        = (long)NBATCH * HD * HP;             // 534560
static constexpr long GBC_OFF     = H_OFF + H_SZ;                       // 535584
static constexpr long GBC_SZ      = (long)NBATCH * NTH * NTH;           // 524288
static constexpr long RECAB_OFF   = GBC_OFF + GBC_SZ;                   // 1059872 (even)
static constexpr long RECAB_SZ    = (long)NBATCH * GRP * CAPG * 2;      // 5636096
static constexpr long RECK_OFF    = RECAB_OFF + RECAB_SZ;
static constexpr long RECK_SZ     = (long)NBATCH * GRP * CAPG;
static constexpr long PART_OFF    = RECK_OFF + RECK_SZ;
static constexpr long PART_SZ     = 256 * 256;
static constexpr long TOTAL_FLOATS = PART_OFF + PART_SZ;                // ~38.3 MB

__device__ __forceinline__ float clamp01(float v) { return fminf(fmaxf(v, 0.f), 1.f); }

__device__ __forceinline__ void decode_lut(const float* __restrict__ lv,
                                           const int* __restrict__ lbase,
                                           float v, int& c1, int& c0) {
    if (v <= 0.f) { c1 = 0; c0 = 0; return; }
    int j = min((int)v, 255);
    int i = lbase[j];
    while (i < 256 && lv[i] < v) ++i;
    c0 = i;
    float u = v - 1.f;
    if (u < 0.f) { c1 = 0; return; }
    int j1 = min((int)u, 255);
    int i1 = lbase[j1];
    while (i1 < 256 && lv[i1] <= u) ++i1;
    c1 = i1;
}

// block-level release-arrive / acquire-spin (fence+atomic pattern proven by matvec finalize)
__device__ __forceinline__ void arrive(int* ctr) {
    __threadfence();          // release each thread's global writes
    __syncthreads();          // all threads fenced before the signal
    if (threadIdx.x == 0)
        __hip_atomic_fetch_add(ctr, 1, __ATOMIC_RELEASE, __HIP_MEMORY_SCOPE_AGENT);
}
__device__ __forceinline__ void spin_until(const int* ctr, int target) {
    if (threadIdx.x == 0) {
        while (__hip_atomic_load(ctr, __ATOMIC_ACQUIRE, __HIP_MEMORY_SCOPE_AGENT) < target)
            __builtin_amdgcn_s_sleep(8);
    }
    __syncthreads();
    __threadfence();          // acquire for all threads
}

// per-phase LDS union
struct BinS {
    float raw[256];
    int   sidx[256];
    float la[256];
    int   lbaseA[257];
    int   lbaseB[257];
    float lx[1025];
    int   lcnt[GRP];
    int   lbs[GRP];
};
struct P2S {
    float lHG[6][257];   // rows 0..2 = H, 3..5 = Gb
    float lT[6][257];
    float lGa[768];      // [s*3 + d]
    float lCsp[3][256];
};
struct ScanS { float s0[4][264]; float s1[4][264]; };
struct MvS   { float Wl[128][32]; float gl[8][128]; int lastFlag; };
static constexpr size_t SMEM_MAX =
    sizeof(MvS) > sizeof(P2S) ? (sizeof(MvS) > sizeof(BinS) ? sizeof(MvS) : sizeof(BinS))
                              : (sizeof(P2S) > sizeof(BinS) ? sizeof(P2S) : sizeof(BinS));

__global__ void __launch_bounds__(256)
k_mega(const float* __restrict__ x, const float* __restrict__ pa,
       const float* __restrict__ pb, const float* __restrict__ W,
       const float* __restrict__ bias, float* __restrict__ out,
       int* __restrict__ doneBin, int* __restrict__ doneP2,
       int* __restrict__ doneSc, int* __restrict__ doneMv, int* __restrict__ gcur,
       float* __restrict__ H, float* __restrict__ GbC,
       float2* __restrict__ recAB, uint32_t* __restrict__ recK,
       float* __restrict__ partial) {
    __shared__ __align__(16) char smem[SMEM_MAX];
    __shared__ float lbR[256];   // sorted phi_b (persists all phases)
    __shared__ int   ibR[256];   // orig idx of sorted phi_b

    int t = threadIdx.x;
    int i = blockIdx.x;          // 0..687

    //======== phase 0: local sorts (every block) + optional bin ========
    {
        BinS& s = *reinterpret_cast<BinS*>(smem);
        bool hasBin = (i < NBATCH * NCH);
        int bb = i / NCH, c = i % NCH;
        int k0 = c * 1024;
        if (hasBin) {   // stage x early to hide latency under the sorts
            for (int p = 0; p < 4; ++p) {
                int kk = k0 + p * 256 + t;
                s.lx[p * 256 + t] = (kk < MPIX) ? x[(long)bb * MPIX + kk] : 0.f;
            }
            if (t == 0) s.lx[1024] = (k0 + 1024 < MPIX) ? x[(long)bb * MPIX + k0 + 1024] : 0.f;
        }
        s.raw[t] = pa[t];
        if (t < GRP) s.lcnt[t] = 0;
        __syncthreads();
        {   // stable rank sort of phi_a
            float v = s.raw[t]; int cc = 0;
            for (int j = 0; j < 256; ++j) { float w = s.raw[j]; cc += (w < v) || (w == v && j < t); }
            s.la[cc] = v; s.sidx[cc] = t;
        }
        __syncthreads();
        int ia_r = (i < 256) ? s.sidx[i] : 0;          // matvec's gathered A-index
        int g    = i % GRP;
        int r0   = g * GW;
        float la0 = s.la[min(r0,     255)];             // phase2's 3 A-thresholds
        float la1 = s.la[min(r0 + 1, 255)];
        float la2 = s.la[min(r0 + 2, 255)];
        {   // LUT A
            float q = (float)t;
            int lo = 0, hi = 256;
            while (lo < hi) { int m = (lo + hi) >> 1; if (s.la[m] < q) lo = m + 1; else hi = m; }
            s.lbaseA[t] = lo;
            if (t == 0) s.lbaseA[256] = 256;
        }
        s.raw[t] = pb[t];
        __syncthreads();
        {   // stable rank sort of phi_b -> reserved
            float v = s.raw[t]; int cc = 0;
            for (int j = 0; j < 256; ++j) { float w = s.raw[j]; cc += (w < v) || (w == v && j < t); }
            lbR[cc] = v; ibR[cc] = t;
        }
        __syncthreads();
        {   // LUT B
            float q = (float)t;
            int lo = 0, hi = 256;
            while (lo < hi) { int m = (lo + hi) >> 1; if (lbR[m] < q) lo = m + 1; else hi = m; }
            s.lbaseB[t] = lo;
            if (t == 0) s.lbaseB[256] = 256;
        }
        __syncthreads();

        if (hasBin) {
            float    av[4], bdv[4];
            uint32_t keyv[4];
            int      g0v[4], g1v[4];
            bool     valv[4];
#pragma unroll
            for (int p = 0; p < 4; ++p) {
                int idx = p * 256 + t;
                int kk = k0 + idx;
                valv[p] = (kk < MPIX);
                g0v[p] = 0; g1v[p] = -1;
                if (valv[p]) {
                    float a  = s.lx[idx];
                    float bd = a - s.lx[idx + 1];
                    int ca1, ca0, cb1, cb0;
                    decode_lut(s.la, s.lbaseA, a,  ca1, ca0);
                    decode_lut(lbR,  s.lbaseB, bd, cb1, cb0);
                    int wa = min(ca0 - ca1, 127);
                    int wb = min(cb0 - cb1, 127);
                    if (cb1 == 0 && wb == 0) { valv[p] = false; continue; }   // dead record
                    av[p] = a; bdv[p] = bd;
                    keyv[p] = (uint32_t)ca1 | ((uint32_t)wa << 9)
                            | ((uint32_t)cb1 << 16) | ((uint32_t)wb << 25);
                    g0v[p] = ca1 / GW;
                    g1v[p] = min(ca1 + max(wa, 1) - 1, 256) / GW;
                    for (int gg = g0v[p]; gg <= g1v[p]; ++gg) atomicAdd(&s.lcnt[gg], 1);
                }
            }
            __syncthreads();
            if (t < GRP) {
                s.lbs[t] = atomicAdd(&gcur[bb * GRP + t], s.lcnt[t]);
                s.lcnt[t] = 0;
            }
            __syncthreads();
#pragma unroll
            for (int p = 0; p < 4; ++p) {
                if (valv[p]) {
                    float2 rec = make_float2(av[p], bdv[p]);
                    for (int gg = g0v[p]; gg <= g1v[p]; ++gg) {
                        int slot = s.lbs[gg] + atomicAdd(&s.lcnt[gg], 1);
                        if (slot < CAPG) {
                            long off = ((long)(bb * GRP + gg)) * CAPG + slot;
                            recAB[off] = rec;
                            recK[off]  = keyv[p];
                        }
                    }
                }
            }
            arrive(&doneBin[bb]);
        }

        //======== phase 1: phase2 (every block has a task: (pb, g)) ========
        int pb = i / GRP;
        spin_until(&doneBin[pb], NCH);   // also the BinS->P2S reuse barrier

        P2S& s2 = *reinterpret_cast<P2S*>(smem);
        int rlen = min(GW, HD - r0);
        for (int j = t; j < 6 * 257; j += 256) (&s2.lHG[0][0])[j] = 0.f;
        for (int j = t; j < 768; j += 256) s2.lGa[j] = 0.f;
        for (int j = t; j < 3 * 256; j += 256) (&s2.lCsp[0][0])[j] = 0.f;
        __syncthreads();

        int cnt = min(__hip_atomic_load(&gcur[pb * GRP + g], __ATOMIC_RELAXED,
                                        __HIP_MEMORY_SCOPE_AGENT), CAPG);
        const long base = ((long)(pb * GRP + g)) * CAPG;
        for (int j = t; j < cnt; j += 256) {
            float2 ab = recAB[base + j];
            uint32_t key = recK[base + j];
            float a = ab.x, bd = ab.y;
            int ca1 = key & 511;
            int wa  = (key >> 9) & 127;
            int cb1 = (key >> 16) & 511;
            int wb  = key >> 25;
            int d = ca1 - r0;
            bool owna = (unsigned)d < (unsigned)rlen;
            int rlo = max(ca1, r0);
            int rhi = min(ca1 + wa, r0 + rlen);
            if (owna) {
                if (cb1 > 0) atomicAdd(&s2.lHG[d][cb1], 1.0f);
                for (int ss = cb1; ss < cb1 + wb; ++ss)
                    atomicAdd(&s2.lGa[ss * 3 + d], clamp01(bd - lbR[ss]));
            }
#pragma unroll
            for (int jj = 0; jj < GW; ++jj) {
                int r = r0 + jj;
                if (r >= rlo && r < rhi) {
                    float laj = (jj == 0) ? la0 : (jj == 1) ? la1 : la2;
                    float f = clamp01(a - laj);
                    if (cb1 > 0) atomicAdd(&s2.lHG[GW + jj][cb1], f);
                    for (int ss = cb1; ss < cb1 + wb; ++ss)
                        atomicAdd(&s2.lCsp[jj][ss], f * clamp01(bd - lbR[ss]));
                }
            }
        }
        __syncthreads();

        float* src = &s2.lHG[0][0];
        float* dst = &s2.lT[0][0];
        for (int dd = 1; dd < 257; dd <<= 1) {
            for (int j = t; j < 6 * 257; j += 256) {
                int cc = j % 257;
                dst[j] = src[j] + ((cc + dd < 257) ? src[j + dd] : 0.f);
            }
            __syncthreads();
            float* tmp = src; src = dst; dst = tmp;
        }
        int rgb = max(0, min(rlen, NTH - r0));
        for (int rr = 0; rr < rgb; ++rr) {
            const float* gbS = src + (GW + rr) * 257;
            GbC[((long)pb * NTH + (r0 + rr)) * NTH + t] = gbS[t + 1] + s2.lCsp[rr][t];
        }
        for (int rr = 0; rr < rlen; ++rr) {
            const float* hS = src + rr * 257;
            float* dsth = H + ((long)pb * HD + (r0 + rr)) * HP;
            for (int q = t; q < 257; q += 256)
                dsth[q] = hS[q] + ((q >= 1) ? s2.lGa[(q - 1) * 3 + rr] : 0.f);
        }
        arrive(&doneP2[pb]);
    }

    //======== phase 2: scanB (blocks 0..519) ========
    if (i >= NBATCH * NSCAN) return;
    {
        int sb = i / NSCAN, quad = i % NSCAN;
        spin_until(&doneP2[sb], GRP);   // also P2S->ScanS reuse barrier

        ScanS& s3 = *reinterpret_cast<ScanS*>(smem);
        int c0 = quad * 4;
        float* Hb = H + (long)sb * HD * HP;
        for (int row = t; row < HD; row += 256) {
            float4 v = *(const float4*)(Hb + (long)row * HP + c0);
            s3.s0[0][row] = v.x; s3.s0[1][row] = v.y; s3.s0[2][row] = v.z; s3.s0[3][row] = v.w;
        }
        __syncthreads();
        float (*src)[264] = s3.s0, (*dst)[264] = s3.s1;
        int col = t >> 6, lane = t & 63;
        for (int d = 1; d < HD; d <<= 1) {
            for (int j = lane; j < HD; j += 64)
                dst[col][j] = src[col][j] + ((j + d < HD) ? src[col][j + d] : 0.f);
            __syncthreads();
            float (*tmp)[264] = src; src = dst; dst = tmp;
        }
        for (int row = t; row < HD; row += 256) {
            float4 v = make_float4(src[0][row], src[1][row], src[2][row], src[3][row]);
            *(float4*)(Hb + (long)row * HP + c0) = v;
        }
        arrive(&doneSc[sb]);
    }

    //======== phase 3: matvec (blocks 0..255) + last-block finalize ========
    if (i >= 256) return;
    {
        for (int b2 = 0; b2 < NBATCH; ++b2) spin_until(&doneSc[b2], NSCAN);

        MvS& s4 = *reinterpret_cast<MvS*>(smem);
        BinS& sb0 = *reinterpret_cast<BinS*>(smem);   // only for historical note; unused
        (void)sb0;
        int r = i;
        // re-extract ia_r is impossible (BinS overwritten) — it was saved in phase 0:
        // NOTE: ia_r register survived all phases.
        int bb2 = t >> 5, o = t & 31;
        float acc = 0.f;
        // recover ia_r: stored below in phase 0 epilogue via register 'mv_iar'
        extern __shared__ char _dummy[];   // (unused; keeps compiler happy)
        (void)_dummy;
        // --- we need ia_r here; it was computed in phase 0 scope. Recompute cheaply:
        // sorted rank r of phi_a -> original index: count-based single pass in registers.
        // Each thread counts how many phi_a[j] are less than phi_a[t] (stable);
        // the thread whose rank == r publishes its original index via LDS.
        {
            float v = pa[t];
            int cc = 0;
            for (int j = 0; j < 256; ++j) {
                float w = pa[j];
                cc += (w < v) || (w == v && j < t);
            }
            if (cc == r) s4.lastFlag = t;    // reuse int slot as scratch
            __syncthreads();
        }
        int ia_r2 = s4.lastFlag;
        __syncthreads();
#pragma unroll
        for (int it = 0; it < 2; ++it) {
            int s0 = it * 128;
            __syncthreads();
            {
                int rr = t >> 1, half = t & 1;
                int wrow = ia_r2 * 256 + ibR[s0 + rr];
                const float4* srcW = reinterpret_cast<const float4*>(W + (long)wrow * 32 + half * 16);
                float4* dstW = reinterpret_cast<float4*>(&s4.Wl[rr][half * 16]);
#pragma unroll
                for (int u = 0; u < 4; ++u) dstW[u] = srcW[u];
            }
            {
                int bS = t >> 5, j4 = (t & 31) * 4;
                int sbc = s0 + j4;
                const float4 gb = *reinterpret_cast<const float4*>(
                    GbC + ((long)bS * NTH + r) * NTH + sbc);
                const float* hp = H + ((long)bS * HD + (r + 1)) * HP + 1 + sbc;
                float4 v;
                v.x = hp[0] + gb.x;
                v.y = hp[1] + gb.y;
                v.z = hp[2] + gb.z;
                v.w = hp[3] + gb.w;
                *reinterpret_cast<float4*>(&s4.gl[bS][j4]) = v;
            }
            __syncthreads();
#pragma unroll 8
            for (int kk = 0; kk < 128; ++kk) acc += s4.gl[bb2][kk] * s4.Wl[kk][o];
        }
        partial[(long)r * 256 + t] = acc;
        __threadfence();
        __syncthreads();
        if (t == 0)
            s4.lastFlag = (__hip_atomic_fetch_add(doneMv, 1, __ATOMIC_ACQ_REL,
                                                  __HIP_MEMORY_SCOPE_AGENT) == 255) ? 1 : 0;
        __syncthreads();
        if (s4.lastFlag) {
            __threadfence();
            float s = 0.f;
#pragma unroll 16
            for (int c2 = 0; c2 < 256; ++c2) s += partial[(long)c2 * 256 + t];
            out[t] = fmaxf(s + bias[t & 31], 0.f);
        }
    }
}

extern "C" void kernel_launch(void* const* d_in, const int* in_sizes, int n_in,
                              void* d_out, int out_size, void* d_ws, size_t ws_size,
                              hipStream_t stream) {
    const float* x    = (const float*)d_in[0];
    const float* pa   = (const float*)d_in[1];
    const float* pb   = (const float*)d_in[2];
    const float* W    = (const float*)d_in[3];
    const float* bias = (const float*)d_in[4];
    float* out = (float*)d_out;
    float* ws  = (float*)d_ws;

    if (ws_size < (size_t)TOTAL_FLOATS * sizeof(float)) {
        fprintf(stderr, "kernel_launch: ws too small: %zu < %zu bytes\n",
                ws_size, (size_t)TOTAL_FLOATS * sizeof(float));
        return;
    }

    int*      doneBin = (int*)(ws + DONEBIN_OFF);
    int*      doneP2  = (int*)(ws + DONEP2_OFF);
    int*      doneSc  = (int*)(ws + DONESC_OFF);
    int*      doneMv  = (int*)(ws + DONEMV_OFF);
    int*      gcur    = (int*)(ws + GCUR_OFF);
    float*    H       = ws + H_OFF;
    float*    GbC     = ws + GBC_OFF;
    float2*   recAB   = (float2*)(ws + RECAB_OFF);
    uint32_t* recK    = (uint32_t*)(ws + RECK_OFF);
    float*    part    = ws + PART_OFF;

    hipMemsetAsync(d_ws, 0, (size_t)CTR_BYTES, stream);
    k_mega<<<dim3(NBLK), dim3(256), 0, stream>>>(
        x, pa, pb, W, bias, out,
        doneBin, doneP2, doneSc, doneMv, gcur,
        H, GbC, recAB, recK, part);
}

// Round 15
// 145.133 us; speedup vs baseline: 4.5295x; 4.5295x over previous
//
#include <hip/hip_runtime.h>
#include <cstdio>
#include <cstdint>

static constexpr int  MPIX   = 51529;   // 227*227
static constexpr int  NBATCH = 8;
static constexpr int  NTH    = 256;
static constexpr int  HD     = 257;     // rank histogram dim (0..256)
static constexpr int  HP     = 260;     // padded H pitch
static constexpr int  GW     = 9;       // rank-group width
static constexpr int  GRP    = 29;      // ceil(257/9); 29*8 = 232 blocks (one wave on 256 CUs)

// ws layout (float slots)
static constexpr long IA_OFF  = 0;      // 256 ints (orig idx of sorted phi_a)
static constexpr long IB_OFF  = 256;    // 256 ints
static constexpr long MVC_OFF = 512;    // 1 int (zeroed by k_fused1 block (0,0))
static constexpr long H_OFF   = 1024;
static constexpr long H_SZ    = (long)NBATCH * HD * HP;    // 534560
static constexpr long GBC_OFF = H_OFF + H_SZ;
static constexpr long GBC_SZ  = (long)NBATCH * NTH * NTH;  // 524288
static constexpr long PART_OFF = GBC_OFF + GBC_SZ;
static constexpr long PART_SZ  = 256 * 256;
static constexpr long TOTAL_FLOATS = PART_OFF + PART_SZ;   // ~4.5 MB

__device__ __forceinline__ float clamp01(float v) { return fminf(fmaxf(v, 0.f), 1.f); }

// LUT decode: c0 = first idx with lv[i] >= v ; c1 = first idx with lv[i] > v-1
__device__ __forceinline__ void decode_lut(const float* __restrict__ lv,
                                           const int* __restrict__ lbase,
                                           float v, int& c1, int& c0) {
    if (v <= 0.f) { c1 = 0; c0 = 0; return; }
    int j = min((int)v, 255);
    int i = lbase[j];
    while (i < 256 && lv[i] < v) ++i;
    c0 = i;
    float u = v - 1.f;
    if (u < 0.f) { c1 = 0; return; }
    int j1 = min((int)u, 255);
    int i1 = lbase[j1];
    while (i1 < 256 && lv[i1] <= u) ++i1;
    c1 = i1;
}

// Node 1: fused sort + direct-from-x accumulate + row-scan + flush.
// Block (g, b): sorts both threshold sets locally, scans batch-b pixels with a
// 2-compare range prefilter on `a`, decodes only relevant pixels, accumulates
// H/Ga/Gb/Csp in LDS, suffix-scans rows along cb1, flushes:
//   H[b][p][q] = rowScanH[p][q] + lGa[q-1][p-r0]   (ca1-scan absorbed into matvec)
//   GbC[b][r][s] = SufGb[r][s+1] + Csp[r][s]
// Block (0,0) publishes ia/ib and zeroes mvc.
__global__ void __launch_bounds__(1024)
k_fused1(const float* __restrict__ x, const float* __restrict__ pa,
         const float* __restrict__ pb,
         int* __restrict__ ia, int* __restrict__ ib, int* __restrict__ mvc,
         float* __restrict__ H, float* __restrict__ GbC) {
    __shared__ float la[256], lb[256];
    __shared__ int   lbA[257], lbB[257];
    __shared__ float lHG[18][257];   // rows 0..8 = H, rows 9..17 = Gb
    __shared__ float lT[18][257];    // scan ping-pong; sort scratch before that
    __shared__ float lGa[256][10];   // [s][ca1-r0]
    __shared__ float lCsp[9][256];

    int t = threadIdx.x;
    int g = blockIdx.x, b = blockIdx.y;
    int r0 = g * GW;
    int rlen = min(GW, HD - r0);

    // ---- sort scratch carved out of lT ----
    float* raw   = &lT[0][0];            // 256 floats
    int*   cnt4v = (int*)&lT[1][0];      // 1024 ints (rows 1..4)
    int*   lidx  = (int*)&lT[5][0];      // 256 ints

    // sort A
    if (t < 256) raw[t] = pa[t];
    __syncthreads();
    {
        int e = t & 255, qd = t >> 8;
        float v = raw[e]; int cc = 0;
        for (int j = qd * 64; j < qd * 64 + 64; ++j) {
            float w = raw[j];
            cc += (w < v) || (w == v && j < e);
        }
        cnt4v[e * 4 + qd] = cc;
    }
    __syncthreads();
    if (t < 256) {
        int r = cnt4v[t * 4] + cnt4v[t * 4 + 1] + cnt4v[t * 4 + 2] + cnt4v[t * 4 + 3];
        la[r] = raw[t];
        lidx[r] = t;
    }
    __syncthreads();
    if (g == 0 && b == 0 && t < 256) ia[t] = lidx[t];
    if (g == 0 && b == 0 && t == 0) *mvc = 0;
    if (t < 257) {   // LUT A
        float q = (float)t;
        int lo = 0, hi = 256;
        while (lo < hi) { int m = (lo + hi) >> 1; if (la[m] < q) lo = m + 1; else hi = m; }
        lbA[t] = lo;
    }
    __syncthreads();
    // sort B (reuse scratch)
    if (t < 256) raw[t] = pb[t];
    __syncthreads();
    {
        int e = t & 255, qd = t >> 8;
        float v = raw[e]; int cc = 0;
        for (int j = qd * 64; j < qd * 64 + 64; ++j) {
            float w = raw[j];
            cc += (w < v) || (w == v && j < e);
        }
        cnt4v[e * 4 + qd] = cc;
    }
    __syncthreads();
    if (t < 256) {
        int r = cnt4v[t * 4] + cnt4v[t * 4 + 1] + cnt4v[t * 4 + 2] + cnt4v[t * 4 + 3];
        lb[r] = raw[t];
        lidx[r] = t;
    }
    __syncthreads();
    if (g == 0 && b == 0 && t < 256) ib[t] = lidx[t];
    if (t < 257) {   // LUT B
        float q = (float)t;
        int lo = 0, hi = 256;
        while (lo < hi) { int m = (lo + hi) >> 1; if (lb[m] < q) lo = m + 1; else hi = m; }
        lbB[t] = lo;
    }
    __syncthreads();

    // zero accumulators (lT may hold sort garbage; scan overwrites it before reading)
    for (int i = t; i < 18 * 257; i += 1024) (&lHG[0][0])[i] = 0.f;
    for (int i = t; i < 256 * 10; i += 1024) (&lGa[0][0])[i] = 0.f;
    for (int i = t; i < 9 * 256; i += 1024) (&lCsp[0][0])[i] = 0.f;
    __syncthreads();

    // relevance bounds (sound with slack: spurious passes decode to nothing)
    int idxHi = r0 + rlen - 1;
    float hiB  = (idxHi >= 256) ? 3.4e38f : la[idxHi] + 1.0f + 0.01f;
    float lo1  = (r0 == 0) ? -3.4e38f : la[r0 - 1] + 1.0f - 0.01f;
    float lo2v = la[r0];        // need a > lo2v (exact compare, no slack)
    float lb0  = lb[0];

    const long kb = (long)b * MPIX;
    for (int k = t; k < MPIX; k += 1024) {
        float a = x[kb + k];
        if (a >= hiB) continue;
        if (a < lo1 && a <= lo2v) continue;
        float a2 = (k + 1 < MPIX) ? x[kb + k + 1] : 0.f;
        float bd = a - a2;
        if (bd <= lb0) continue;          // cb1==0 && wb==0: contributes nothing read
        int ca1, ca0, cb1, cb0;
        decode_lut(la, lbA, a,  ca1, ca0);
        decode_lut(lb, lbB, bd, cb1, cb0);
        int wa = ca0 - ca1;
        int wb = cb0 - cb1;
        int d = ca1 - r0;
        bool owna = (unsigned)d < (unsigned)rlen;
        int rlo = max(ca1, r0);
        int rhi = min(ca1 + wa, r0 + rlen);   // <= ca0 <= 256 -> r <= 255, la[r] safe
        if (owna) {
            if (cb1 > 0) atomicAdd(&lHG[d][cb1], 1.0f);
            for (int ss = cb1; ss < cb1 + wb; ++ss)
                atomicAdd(&lGa[ss][d], clamp01(bd - lb[ss]));
        }
        for (int r = rlo; r < rhi; ++r) {
            float f = clamp01(a - la[r]);
            int rr = r - r0;
            if (cb1 > 0) atomicAdd(&lHG[9 + rr][cb1], f);
            for (int ss = cb1; ss < cb1 + wb; ++ss)
                atomicAdd(&lCsp[rr][ss], f * clamp01(bd - lb[ss]));
        }
    }
    __syncthreads();

    // combined suffix-scan of 18 rows along cb1 (9 passes)
    float* src = &lHG[0][0];
    float* dst = &lT[0][0];
    for (int dd = 1; dd < 257; dd <<= 1) {
        for (int i = t; i < 18 * 257; i += 1024) {
            int cc = i % 257;
            dst[i] = src[i] + ((cc + dd < 257) ? src[i + dd] : 0.f);
        }
        __syncthreads();
        float* tmp = src; src = dst; dst = tmp;
    }
    int rgb = max(0, min(rlen, NTH - r0));
    for (int rr = 0; rr < rgb; ++rr) {
        const float* gbS = src + (9 + rr) * 257;
        float* dstg = GbC + ((long)b * NTH + (r0 + rr)) * NTH;
        for (int ss = t; ss < 256; ss += 1024) dstg[ss] = gbS[ss + 1] + lCsp[rr][ss];
    }
    for (int rr = 0; rr < rlen; ++rr) {
        const float* hS = src + rr * 257;
        float* dsth = H + ((long)b * HD + (r0 + rr)) * HP;
        for (int q = t; q < 1024 && q < 257; q += 1024) {}   // (no-op; kept simple below)
        for (int q = t; q < 257; q += 1024)
            dsth[q] = hS[q] + ((q >= 1) ? lGa[q - 1][rr] : 0.f);
    }
}

// Node 2: scan-absorbed matvec. Block q-1 handles glcm column s=q-1 for all batches:
//   acc[b][o] = sum_r GbC[b][r][s]*Wg[r][o] + sum_r Hpart[b][r+1][q]*prefW[r][o]
// where Wg[r] = W[ia[r]*256+ib[s]] and prefW[r] = sum_{j<=r} Wg[j]  (running prefix
// replaces the ca1-direction suffix scan of H exactly).
__global__ void __launch_bounds__(256)
k_mv2(const float* __restrict__ H, const float* __restrict__ GbC,
      const float* __restrict__ W,
      const int* __restrict__ ia, const int* __restrict__ ib,
      float* __restrict__ partial, int* __restrict__ mvc,
      const float* __restrict__ bias, float* __restrict__ out) {
    __shared__ float Wl[256][33];
    __shared__ float Hc[8][257];
    __shared__ float Gc[8][257];
    __shared__ int   iaL[256];
    __shared__ int   ibq;
    __shared__ int   lastFlag;
    int t = threadIdx.x;
    int q = blockIdx.x + 1;          // 1..256 ; s = q-1
    iaL[t] = ia[t];
    if (t == 0) ibq = ib[q - 1];
    __syncthreads();
    for (int idx = t; idx < 256 * 32; idx += 256) {
        int r = idx >> 5, o = idx & 31;
        Wl[r][o] = W[((long)iaL[r] * 256 + ibq) * 32 + o];
    }
    for (int idx = t; idx < 2048; idx += 256) {
        int bb = idx >> 8, p = idx & 255;
        Hc[bb][p] = H[((long)bb * HD + (p + 1)) * HP + q];
        Gc[bb][p] = GbC[((long)bb * NTH + p) * NTH + (q - 1)];
    }
    __syncthreads();
    int b = t >> 5, o = t & 31;
    float runW = 0.f, acc = 0.f;
#pragma unroll 8
    for (int r = 0; r < 256; ++r) {
        float w_ = Wl[r][o];
        runW += w_;
        acc += Gc[b][r] * w_ + Hc[b][r] * runW;
    }
    partial[(long)blockIdx.x * 256 + t] = acc;
    __threadfence();
    if (t == 0) lastFlag = (atomicAdd(mvc, 1) == 255) ? 1 : 0;
    __syncthreads();
    if (lastFlag) {
        __threadfence();
        float s = 0.f;
#pragma unroll 16
        for (int c2 = 0; c2 < 256; ++c2) s += partial[(long)c2 * 256 + t];
        out[t] = fmaxf(s + bias[t & 31], 0.f);
    }
}

extern "C" void kernel_launch(void* const* d_in, const int* in_sizes, int n_in,
                              void* d_out, int out_size, void* d_ws, size_t ws_size,
                              hipStream_t stream) {
    const float* x    = (const float*)d_in[0];
    const float* pa   = (const float*)d_in[1];
    const float* pb   = (const float*)d_in[2];
    const float* W    = (const float*)d_in[3];
    const float* bias = (const float*)d_in[4];
    float* out = (float*)d_out;
    float* ws  = (float*)d_ws;

    if (ws_size < (size_t)TOTAL_FLOATS * sizeof(float)) {
        fprintf(stderr, "kernel_launch: ws too small: %zu < %zu bytes\n",
                ws_size, (size_t)TOTAL_FLOATS * sizeof(float));
        return;
    }

    int*   ia   = (int*)(ws + IA_OFF);
    int*   ib   = (int*)(ws + IB_OFF);
    int*   mvc  = (int*)(ws + MVC_OFF);
    float* H    = ws + H_OFF;
    float* GbC  = ws + GBC_OFF;
    float* part = ws + PART_OFF;

    k_fused1<<<dim3(GRP, NBATCH), dim3(1024), 0, stream>>>(
        x, pa, pb, ia, ib, mvc, H, GbC);
    k_mv2<<<dim3(256), dim3(256), 0, stream>>>(
        H, GbC, W, ia, ib, part, mvc, bias, out);
}